// Round 2
// baseline (164.074 us; speedup 1.0000x reference)
//
#include <hip/hip_runtime.h>
#include <hip/hip_bf16.h>
#include <stdint.h>

typedef __attribute__((ext_vector_type(8))) short s16x8;          // 8 bf16 (4 VGPRs)
typedef __attribute__((ext_vector_type(8))) unsigned short u16x8;
typedef __attribute__((ext_vector_type(4))) float f32x4;

#define D_FEAT 128
#define H2 128
#define BLOCK_THREADS 512
#define WAVES 8
#define MW 64                        // edges per wave
#define EDGES_PER_BLOCK (WAVES * MW) // 512

__device__ __forceinline__ unsigned short f2bf(float f) {
  uint32_t u = __float_as_uint(f);
  return (unsigned short)((u + 0x7fffu + ((u >> 16) & 1u)) >> 16);  // RNE
}

// ---------------- pre-conversion kernels ----------------
__global__ void k_cvt_x(const float* __restrict__ x, unsigned short* __restrict__ xb, int n8) {
  int i = blockIdx.x * blockDim.x + threadIdx.x;
  if (i >= n8) return;
  const f32x4* p = (const f32x4*)x + (size_t)i * 2;
  f32x4 a = p[0], b = p[1];
  u16x8 o;
  o[0] = f2bf(a[0]); o[1] = f2bf(a[1]); o[2] = f2bf(a[2]); o[3] = f2bf(a[3]);
  o[4] = f2bf(b[0]); o[5] = f2bf(b[1]); o[6] = f2bf(b[2]); o[7] = f2bf(b[3]);
  ((u16x8*)xb)[i] = o;
}

// W1 [256][128] fp32 row-major -> swizzled bf16 W1^T tile (64KB) in ws.
// Element (n,k) stored at n*256 + ((chunk ^ (n&7))<<3) + (k&7), chunk = k>>3.
__global__ void k_cvt_w1(const float* __restrict__ W1, unsigned short* __restrict__ w1t) {
  int tid = blockIdx.x * blockDim.x + threadIdx.x;   // 0..4095
  int chunk = tid >> 7;                               // 0..31
  int n = tid & 127;
  u16x8 o;
#pragma unroll
  for (int j = 0; j < 8; ++j)
    o[j] = f2bf(W1[(chunk * 8 + j) * H2 + n]);
  *(u16x8*)(w1t + (n << 8) + ((chunk ^ (n & 7)) << 3)) = o;
}

// ---------------- main fused kernel ----------------
template <bool XBF>
__global__ __launch_bounds__(BLOCK_THREADS, 2)
void k_edge_mlp(const float* __restrict__ xf,
                const unsigned short* __restrict__ xb,
                const int* __restrict__ eli,      // int32: [2][E]
                const float* __restrict__ W1,
                const unsigned short* __restrict__ w1ws,
                const float* __restrict__ b1,
                const float* __restrict__ W2,
                const float* __restrict__ b2,
                float* __restrict__ out, int E, int nNodes)
{
  __shared__ unsigned short w1t[H2 * 256];   // 64KB, swizzled W1^T
  const int t    = threadIdx.x;
  const int lane = t & 63;
  const int wid  = t >> 6;
  const int c    = lane & 15;   // A-row-in-frag / B-col-in-frag
  const int g    = lane >> 4;   // k-subgroup (8 consecutive k)

  // ---- stage W1^T (bf16, swizzled) into LDS ----
  if (XBF) {
#pragma unroll
    for (int i = 0; i < 8; ++i) {
      int idx = i * BLOCK_THREADS + t;              // 4096 chunks of 16B
      ((u16x8*)w1t)[idx] = ((const u16x8*)w1ws)[idx];
    }
  } else {
    int cg = t >> 7;          // 0..3
    int n  = t & 127;
#pragma unroll
    for (int i = 0; i < 8; ++i) {
      int ch = cg + 4 * i;    // 0..31
      u16x8 o;
#pragma unroll
      for (int j = 0; j < 8; ++j)
        o[j] = f2bf(W1[(ch * 8 + j) * H2 + n]);
      *(u16x8*)(w1t + (n << 8) + ((ch ^ (n & 7)) << 3)) = o;
    }
  }

  // ---- per-lane edge index bases (global loads overlap the staging) ----
  const int wbase = blockIdx.x * EDGES_PER_BLOCK + wid * MW;
  long noff_r[4], noff_c[4];
#pragma unroll
  for (int m = 0; m < 4; ++m) {
    int e = wbase + m * 16 + c;
    e = e < E ? e : E - 1;
    int nr = eli[e];
    int nc = eli[E + e];
    nr = nr < 0 ? 0 : (nr >= nNodes ? nNodes - 1 : nr);   // defensive clamp
    nc = nc < 0 ? 0 : (nc >= nNodes ? nNodes - 1 : nc);
    noff_r[m] = (long)nr * D_FEAT;
    noff_c[m] = (long)nc * D_FEAT;
  }

  __syncthreads();

  // A-fragment gather: kk selects 32-wide K slice; kk<4 -> row node, else col node
  auto loadA = [&](int kk, s16x8* dst) {
#pragma unroll
    for (int m = 0; m < 4; ++m) {
      long base = (kk < 4 ? noff_r[m] : noff_c[m]) + ((kk & 3) * 32 + g * 8);
      if (XBF) {
        dst[m] = *(const s16x8*)(xb + base);
      } else {
        const f32x4* p = (const f32x4*)(xf + base);
        f32x4 a = p[0], b = p[1];
        s16x8 v;
        v[0] = (short)f2bf(a[0]); v[1] = (short)f2bf(a[1]);
        v[2] = (short)f2bf(a[2]); v[3] = (short)f2bf(a[3]);
        v[4] = (short)f2bf(b[0]); v[5] = (short)f2bf(b[1]);
        v[6] = (short)f2bf(b[2]); v[7] = (short)f2bf(b[3]);
        dst[m] = v;
      }
    }
  };

  f32x4 acc[4][8];
#pragma unroll
  for (int m = 0; m < 4; ++m)
#pragma unroll
    for (int f = 0; f < 8; ++f) {
      f32x4 z = {0.f, 0.f, 0.f, 0.f};
      acc[m][f] = z;
    }

  s16x8 abuf[2][4];
  loadA(0, abuf[0]);
  loadA(1, abuf[1]);

#pragma unroll
  for (int kk = 0; kk < 8; ++kk) {
#pragma unroll
    for (int f = 0; f < 8; ++f) {
      int n = f * 16 + c;
      s16x8 bfrag = *(const s16x8*)(w1t + (n << 8) + (((kk * 4 + g) ^ (n & 7)) << 3));
#pragma unroll
      for (int m = 0; m < 4; ++m)
        acc[m][f] = __builtin_amdgcn_mfma_f32_16x16x32_bf16(abuf[kk & 1][m], bfrag, acc[m][f], 0, 0, 0);
    }
    if (kk + 2 < 8) loadA(kk + 2, abuf[kk & 1]);
  }

  // ---- fused epilogue: relu(h + b1) @ W2 + b2, fp32 ----
  float b1v[8], w2v[8];
#pragma unroll
  for (int f = 0; f < 8; ++f) {
    b1v[f] = b1[f * 16 + c];
    w2v[f] = W2[f * 16 + c];
  }
  const float b2s = b2[0];

#pragma unroll
  for (int m = 0; m < 4; ++m) {
    float sr[4];
#pragma unroll
    for (int r = 0; r < 4; ++r) {
      float s = 0.f;
#pragma unroll
      for (int f = 0; f < 8; ++f) {
        float h = acc[m][f][r] + b1v[f];
        h = h > 0.f ? h : 0.f;
        s += h * w2v[f];
      }
#pragma unroll
      for (int msk = 1; msk < 16; msk <<= 1)
        s += __shfl_xor(s, msk, 64);
      sr[r] = s;
    }
    int ebase = wbase + m * 16 + g * 4;
    if (c == 0 && ebase < E) {
      f32x4 o = {sr[0] + b2s, sr[1] + b2s, sr[2] + b2s, sr[3] + b2s};
      *(f32x4*)(out + ebase) = o;
    }
  }
}

extern "C" void kernel_launch(void* const* d_in, const int* in_sizes, int n_in,
                              void* d_out, int out_size, void* d_ws, size_t ws_size,
                              hipStream_t stream) {
  const float* x   = (const float*)d_in[0];
  const int*   eli = (const int*)d_in[1];     // int32 per harness contract
  const float* W1  = (const float*)d_in[2];
  const float* b1  = (const float*)d_in[3];
  const float* W2  = (const float*)d_in[4];
  const float* b2  = (const float*)d_in[5];
  float* out = (float*)d_out;

  const int E      = in_sizes[1] / 2;
  const int nNodes = in_sizes[0] / D_FEAT;

  const size_t xbytes = (size_t)nNodes * D_FEAT * 2;   // bf16 copy of x
  const size_t need   = xbytes + 65536;                // + swizzled W1^T
  const bool bfpath   = (ws_size >= need);

  const int grid = (E + EDGES_PER_BLOCK - 1) / EDGES_PER_BLOCK;

  if (bfpath) {
    unsigned short* xbw  = (unsigned short*)d_ws;
    unsigned short* w1tw = (unsigned short*)((char*)d_ws + xbytes);
    int n8 = nNodes * D_FEAT / 8;
    k_cvt_x<<<(n8 + 255) / 256, 256, 0, stream>>>(x, xbw, n8);
    k_cvt_w1<<<16, 256, 0, stream>>>(W1, w1tw);
    k_edge_mlp<true><<<grid, BLOCK_THREADS, 0, stream>>>(
        x, xbw, eli, W1, w1tw, b1, W2, b2, out, E, nNodes);
  } else {
    k_edge_mlp<false><<<grid, BLOCK_THREADS, 0, stream>>>(
        x, nullptr, eli, W1, nullptr, b1, W2, b2, out, E, nNodes);
  }
}

// Round 3
// 157.791 us; speedup vs baseline: 1.0398x; 1.0398x over previous
//
#include <hip/hip_runtime.h>
#include <hip/hip_bf16.h>
#include <stdint.h>

typedef __attribute__((ext_vector_type(8))) short s16x8;          // 8 bf16 (4 VGPRs)
typedef __attribute__((ext_vector_type(8))) unsigned short u16x8;
typedef __attribute__((ext_vector_type(4))) float f32x4;

#define D_FEAT 128
#define H2 128
#define BLOCK_THREADS 512
#define WAVES 8
#define MW 64                        // edges per wave
#define EDGES_PER_BLOCK (WAVES * MW) // 512

__device__ __forceinline__ unsigned short f2bf(float f) {
  uint32_t u = __float_as_uint(f);
  return (unsigned short)((u + 0x7fffu + ((u >> 16) & 1u)) >> 16);  // RNE
}

// ---------------- pre-conversion kernels ----------------
__global__ void k_cvt_x(const float* __restrict__ x, unsigned short* __restrict__ xb, int n8) {
  int i = blockIdx.x * blockDim.x + threadIdx.x;
  if (i >= n8) return;
  const f32x4* p = (const f32x4*)x + (size_t)i * 2;
  f32x4 a = p[0], b = p[1];
  u16x8 o;
  o[0] = f2bf(a[0]); o[1] = f2bf(a[1]); o[2] = f2bf(a[2]); o[3] = f2bf(a[3]);
  o[4] = f2bf(b[0]); o[5] = f2bf(b[1]); o[6] = f2bf(b[2]); o[7] = f2bf(b[3]);
  ((u16x8*)xb)[i] = o;
}

// W1 [256][128] fp32 row-major -> swizzled bf16 W1^T tile (64KB) in ws.
// Element (n,k) stored at n*256 + ((chunk ^ (n&7))<<3) + (k&7), chunk = k>>3.
__global__ void k_cvt_w1(const float* __restrict__ W1, unsigned short* __restrict__ w1t) {
  int tid = blockIdx.x * blockDim.x + threadIdx.x;   // 0..4095
  int chunk = tid >> 7;                               // 0..31
  int n = tid & 127;
  u16x8 o;
#pragma unroll
  for (int j = 0; j < 8; ++j)
    o[j] = f2bf(W1[(chunk * 8 + j) * H2 + n]);
  *(u16x8*)(w1t + (n << 8) + ((chunk ^ (n & 7)) << 3)) = o;
}

// ---------------- main fused kernel ----------------
template <bool XBF>
__global__ __launch_bounds__(BLOCK_THREADS, 2)
void k_edge_mlp(const float* __restrict__ xf,
                const unsigned short* __restrict__ xb,
                const int* __restrict__ eli,      // int32: [2][E]
                const float* __restrict__ W1,
                const unsigned short* __restrict__ w1ws,
                const float* __restrict__ b1,
                const float* __restrict__ W2,
                const float* __restrict__ b2,
                float* __restrict__ out, int E, int nNodes)
{
  __shared__ unsigned short w1t[H2 * 256];   // 64KB, swizzled W1^T
  const int t    = threadIdx.x;
  const int lane = t & 63;
  const int wid  = t >> 6;
  const int c    = lane & 15;   // A-row-in-frag / B-col-in-frag
  const int g    = lane >> 4;   // k-subgroup (8 consecutive k)

  // ---- stage W1^T (bf16, swizzled) into LDS ----
  if (XBF) {
#pragma unroll
    for (int i = 0; i < 8; ++i) {
      int idx = i * BLOCK_THREADS + t;              // 4096 chunks of 16B
      ((u16x8*)w1t)[idx] = ((const u16x8*)w1ws)[idx];
    }
  } else {
    int cg = t >> 7;          // 0..3
    int n  = t & 127;
#pragma unroll
    for (int i = 0; i < 8; ++i) {
      int ch = cg + 4 * i;    // 0..31
      u16x8 o;
#pragma unroll
      for (int j = 0; j < 8; ++j)
        o[j] = f2bf(W1[(ch * 8 + j) * H2 + n]);
      *(u16x8*)(w1t + (n << 8) + ((ch ^ (n & 7)) << 3)) = o;
    }
  }

  // ---- per-lane edge index bases ----
  const int wbase = blockIdx.x * EDGES_PER_BLOCK + wid * MW;
  unsigned noff_r[4], noff_c[4];   // element offsets into xb (fits 32-bit)
#pragma unroll
  for (int m = 0; m < 4; ++m) {
    int e = wbase + m * 16 + c;
    e = e < E ? e : E - 1;
    int nr = eli[e];
    int nc = eli[E + e];
    nr = nr < 0 ? 0 : (nr >= nNodes ? nNodes - 1 : nr);   // defensive clamp
    nc = nc < 0 ? 0 : (nc >= nNodes ? nNodes - 1 : nc);
    noff_r[m] = (unsigned)nr * D_FEAT;
    noff_c[m] = (unsigned)nc * D_FEAT;
  }

  __syncthreads();

  // A-fragment gather: kk selects 32-wide K slice; kk<4 -> row node, else col node
  auto loadA = [&](int kk, s16x8* dst) {
#pragma unroll
    for (int m = 0; m < 4; ++m) {
      unsigned base = (kk < 4 ? noff_r[m] : noff_c[m]) + (unsigned)((kk & 3) * 32 + g * 8);
      if (XBF) {
        dst[m] = *(const s16x8*)(xb + base);
      } else {
        const f32x4* p = (const f32x4*)(xf + base);
        f32x4 a = p[0], b = p[1];
        s16x8 v;
        v[0] = (short)f2bf(a[0]); v[1] = (short)f2bf(a[1]);
        v[2] = (short)f2bf(a[2]); v[3] = (short)f2bf(a[3]);
        v[4] = (short)f2bf(b[0]); v[5] = (short)f2bf(b[1]);
        v[6] = (short)f2bf(b[2]); v[7] = (short)f2bf(b[3]);
        dst[m] = v;
      }
    }
  };

  f32x4 acc[4][8];
#pragma unroll
  for (int m = 0; m < 4; ++m)
#pragma unroll
    for (int f = 0; f < 8; ++f) {
      f32x4 z = {0.f, 0.f, 0.f, 0.f};
      acc[m][f] = z;
    }

  // depth-4 software pipeline: abuf slots hold kk..kk+3. Lead time ~4 kk-steps
  // (~1240 cyc wall at 2 waves/SIMD) covers HBM-miss gather latency (~900 cyc).
  s16x8 abuf[4][4];
  loadA(0, abuf[0]);
  loadA(1, abuf[1]);
  loadA(2, abuf[2]);
  loadA(3, abuf[3]);

#pragma unroll
  for (int kk = 0; kk < 8; ++kk) {
    __builtin_amdgcn_s_setprio(1);
#pragma unroll
    for (int f = 0; f < 8; ++f) {
      int n = f * 16 + c;
      s16x8 bfrag = *(const s16x8*)(w1t + (n << 8) + (((kk * 4 + g) ^ (n & 7)) << 3));
#pragma unroll
      for (int m = 0; m < 4; ++m)
        acc[m][f] = __builtin_amdgcn_mfma_f32_16x16x32_bf16(abuf[kk & 3][m], bfrag, acc[m][f], 0, 0, 0);
    }
    __builtin_amdgcn_s_setprio(0);
    if (kk < 4) loadA(kk + 4, abuf[kk]);   // refill the slot consumed this iteration
  }

  // ---- fused epilogue: relu(h + b1) @ W2 + b2, fp32 ----
  float b1v[8], w2v[8];
#pragma unroll
  for (int f = 0; f < 8; ++f) {
    b1v[f] = b1[f * 16 + c];
    w2v[f] = W2[f * 16 + c];
  }
  const float b2s = b2[0];

#pragma unroll
  for (int m = 0; m < 4; ++m) {
    float sr[4];
#pragma unroll
    for (int r = 0; r < 4; ++r) {
      float s = 0.f;
#pragma unroll
      for (int f = 0; f < 8; ++f) {
        float h = acc[m][f][r] + b1v[f];
        h = h > 0.f ? h : 0.f;
        s += h * w2v[f];
      }
#pragma unroll
      for (int msk = 1; msk < 16; msk <<= 1)
        s += __shfl_xor(s, msk, 64);
      sr[r] = s;
    }
    int ebase = wbase + m * 16 + g * 4;
    if (c == 0 && ebase < E) {
      f32x4 o = {sr[0] + b2s, sr[1] + b2s, sr[2] + b2s, sr[3] + b2s};
      *(f32x4*)(out + ebase) = o;
    }
  }
}

extern "C" void kernel_launch(void* const* d_in, const int* in_sizes, int n_in,
                              void* d_out, int out_size, void* d_ws, size_t ws_size,
                              hipStream_t stream) {
  const float* x   = (const float*)d_in[0];
  const int*   eli = (const int*)d_in[1];     // int32 per harness contract
  const float* W1  = (const float*)d_in[2];
  const float* b1  = (const float*)d_in[3];
  const float* W2  = (const float*)d_in[4];
  const float* b2  = (const float*)d_in[5];
  float* out = (float*)d_out;

  const int E      = in_sizes[1] / 2;
  const int nNodes = in_sizes[0] / D_FEAT;

  const size_t xbytes = (size_t)nNodes * D_FEAT * 2;   // bf16 copy of x
  const size_t need   = xbytes + 65536;                // + swizzled W1^T
  const bool bfpath   = (ws_size >= need);

  const int grid = (E + EDGES_PER_BLOCK - 1) / EDGES_PER_BLOCK;

  if (bfpath) {
    unsigned short* xbw  = (unsigned short*)d_ws;
    unsigned short* w1tw = (unsigned short*)((char*)d_ws + xbytes);
    int n8 = nNodes * D_FEAT / 8;
    k_cvt_x<<<(n8 + 255) / 256, 256, 0, stream>>>(x, xbw, n8);
    k_cvt_w1<<<16, 256, 0, stream>>>(W1, w1tw);
    k_edge_mlp<true><<<grid, BLOCK_THREADS, 0, stream>>>(
        x, xbw, eli, W1, w1tw, b1, W2, b2, out, E, nNodes);
  } else {
    k_edge_mlp<false><<<grid, BLOCK_THREADS, 0, stream>>>(
        x, nullptr, eli, W1, nullptr, b1, W2, b2, out, E, nNodes);
  }
}

// Round 4
// 140.673 us; speedup vs baseline: 1.1663x; 1.1217x over previous
//
#include <hip/hip_runtime.h>
#include <hip/hip_bf16.h>
#include <stdint.h>

typedef __attribute__((ext_vector_type(8))) short s16x8;          // 8 bf16 (4 VGPRs)
typedef __attribute__((ext_vector_type(8))) unsigned short u16x8;
typedef __attribute__((ext_vector_type(4))) float f32x4;

#define D_FEAT 128
#define H2 128
#define BLOCK_THREADS 512
#define WAVES 8
#define MW 32                        // edges per wave (M-tile) — sized so total regs <= 128
#define EDGES_PER_BLOCK (WAVES * MW) // 256

__device__ __forceinline__ unsigned short f2bf(float f) {
  uint32_t u = __float_as_uint(f);
  return (unsigned short)((u + 0x7fffu + ((u >> 16) & 1u)) >> 16);  // RNE
}

// ---------------- pre-conversion kernels ----------------
__global__ void k_cvt_x(const float* __restrict__ x, unsigned short* __restrict__ xb, int n8) {
  int i = blockIdx.x * blockDim.x + threadIdx.x;
  if (i >= n8) return;
  const f32x4* p = (const f32x4*)x + (size_t)i * 2;
  f32x4 a = p[0], b = p[1];
  u16x8 o;
  o[0] = f2bf(a[0]); o[1] = f2bf(a[1]); o[2] = f2bf(a[2]); o[3] = f2bf(a[3]);
  o[4] = f2bf(b[0]); o[5] = f2bf(b[1]); o[6] = f2bf(b[2]); o[7] = f2bf(b[3]);
  ((u16x8*)xb)[i] = o;
}

// W1 [256][128] fp32 row-major -> swizzled bf16 W1^T tile (64KB) in ws.
// Element (n,k) stored at n*256 + ((chunk ^ (n&7))<<3) + (k&7), chunk = k>>3.
__global__ void k_cvt_w1(const float* __restrict__ W1, unsigned short* __restrict__ w1t) {
  int tid = blockIdx.x * blockDim.x + threadIdx.x;   // 0..4095
  int chunk = tid >> 7;                               // 0..31
  int n = tid & 127;
  u16x8 o;
#pragma unroll
  for (int j = 0; j < 8; ++j)
    o[j] = f2bf(W1[(chunk * 8 + j) * H2 + n]);
  *(u16x8*)(w1t + (n << 8) + ((chunk ^ (n & 7)) << 3)) = o;
}

// ---------------- main fused kernel ----------------
template <bool XBF>
__global__ __launch_bounds__(BLOCK_THREADS, 4)   // target 4 waves/SIMD => 2 blocks/CU
void k_edge_mlp(const float* __restrict__ xf,
                const unsigned short* __restrict__ xb,
                const int* __restrict__ eli,      // int32: [2][E]
                const float* __restrict__ W1,
                const unsigned short* __restrict__ w1ws,
                const float* __restrict__ b1,
                const float* __restrict__ W2,
                const float* __restrict__ b2,
                float* __restrict__ out, int E, int nNodes)
{
  __shared__ unsigned short w1t[H2 * 256];   // 64KB, swizzled W1^T
  const int t    = threadIdx.x;
  const int lane = t & 63;
  const int wid  = t >> 6;
  const int c    = lane & 15;   // A-row-in-frag / B-col-in-frag
  const int g    = lane >> 4;   // k-subgroup (8 consecutive k)

  // ---- stage W1^T (bf16, swizzled) into LDS ----
  if (XBF) {
#pragma unroll
    for (int i = 0; i < 8; ++i) {
      int idx = i * BLOCK_THREADS + t;              // 4096 chunks of 16B
      ((u16x8*)w1t)[idx] = ((const u16x8*)w1ws)[idx];
    }
  } else {
    int cg = t >> 7;          // 0..3
    int n  = t & 127;
#pragma unroll
    for (int i = 0; i < 8; ++i) {
      int ch = cg + 4 * i;    // 0..31
      u16x8 o;
#pragma unroll
      for (int j = 0; j < 8; ++j)
        o[j] = f2bf(W1[(ch * 8 + j) * H2 + n]);
      *(u16x8*)(w1t + (n << 8) + ((ch ^ (n & 7)) << 3)) = o;
    }
  }

  // ---- per-lane edge node pointers (2 edges per lane: m=0,1) ----
  const int wbase = blockIdx.x * EDGES_PER_BLOCK + wid * MW;
  const unsigned short* pr[2];
  const unsigned short* pc[2];
  const float* prf[2];
  const float* pcf[2];
#pragma unroll
  for (int m = 0; m < 2; ++m) {
    int e = wbase + m * 16 + c;
    e = e < E ? e : E - 1;
    int nr = eli[e];
    int nc = eli[E + e];
    nr = nr < 0 ? 0 : (nr >= nNodes ? nNodes - 1 : nr);   // defensive clamp
    nc = nc < 0 ? 0 : (nc >= nNodes ? nNodes - 1 : nc);
    if (XBF) {
      pr[m] = xb + (unsigned)nr * D_FEAT + g * 8;   // g*8 folded into base;
      pc[m] = xb + (unsigned)nc * D_FEAT + g * 8;   // kk slice becomes imm offset
    } else {
      prf[m] = xf + (unsigned)nr * D_FEAT + g * 8;
      pcf[m] = xf + (unsigned)nc * D_FEAT + g * 8;
    }
  }

  __syncthreads();

  // A-fragment gather: kk selects 32-wide K slice; kk<4 -> row node, else col node
  auto loadA = [&](int kk, s16x8* dst) {
#pragma unroll
    for (int m = 0; m < 2; ++m) {
      if (XBF) {
        const unsigned short* p = (kk < 4 ? pr[m] : pc[m]);
        dst[m] = *(const s16x8*)(p + (kk & 3) * 32);   // compile-time imm offset
      } else {
        const float* p = (kk < 4 ? prf[m] : pcf[m]) + (kk & 3) * 32;
        const f32x4* q = (const f32x4*)p;
        f32x4 a = q[0], b = q[1];
        s16x8 v;
        v[0] = (short)f2bf(a[0]); v[1] = (short)f2bf(a[1]);
        v[2] = (short)f2bf(a[2]); v[3] = (short)f2bf(a[3]);
        v[4] = (short)f2bf(b[0]); v[5] = (short)f2bf(b[1]);
        v[6] = (short)f2bf(b[2]); v[7] = (short)f2bf(b[3]);
        dst[m] = v;
      }
    }
  };

  f32x4 acc[2][8];
#pragma unroll
  for (int m = 0; m < 2; ++m)
#pragma unroll
    for (int f = 0; f < 8; ++f) {
      f32x4 z = {0.f, 0.f, 0.f, 0.f};
      acc[m][f] = z;
    }

  // depth-2 software pipeline (16 regs) — occupancy does the latency hiding now
  s16x8 abuf[2][2];
  loadA(0, abuf[0]);
  loadA(1, abuf[1]);

#pragma unroll
  for (int kk = 0; kk < 8; ++kk) {
    __builtin_amdgcn_s_setprio(1);
#pragma unroll
    for (int f = 0; f < 8; ++f) {
      int n = f * 16 + c;
      s16x8 bfrag = *(const s16x8*)(w1t + (n << 8) + (((kk * 4 + g) ^ (n & 7)) << 3));
#pragma unroll
      for (int m = 0; m < 2; ++m)
        acc[m][f] = __builtin_amdgcn_mfma_f32_16x16x32_bf16(abuf[kk & 1][m], bfrag, acc[m][f], 0, 0, 0);
    }
    __builtin_amdgcn_s_setprio(0);
    if (kk < 6) loadA(kk + 2, abuf[kk & 1]);   // refill slot consumed this iteration
  }

  // ---- fused epilogue: relu(h + b1) @ W2 + b2, fp32 ----
  float b1v[8], w2v[8];
#pragma unroll
  for (int f = 0; f < 8; ++f) {
    b1v[f] = b1[f * 16 + c];
    w2v[f] = W2[f * 16 + c];
  }
  const float b2s = b2[0];

#pragma unroll
  for (int m = 0; m < 2; ++m) {
    float sr[4];
#pragma unroll
    for (int r = 0; r < 4; ++r) {
      float s = 0.f;
#pragma unroll
      for (int f = 0; f < 8; ++f) {
        float h = acc[m][f][r] + b1v[f];
        h = h > 0.f ? h : 0.f;
        s += h * w2v[f];
      }
#pragma unroll
      for (int msk = 1; msk < 16; msk <<= 1)
        s += __shfl_xor(s, msk, 64);
      sr[r] = s;
    }
    int ebase = wbase + m * 16 + g * 4;
    if (c == 0 && ebase < E) {
      f32x4 o = {sr[0] + b2s, sr[1] + b2s, sr[2] + b2s, sr[3] + b2s};
      *(f32x4*)(out + ebase) = o;
    }
  }
}

extern "C" void kernel_launch(void* const* d_in, const int* in_sizes, int n_in,
                              void* d_out, int out_size, void* d_ws, size_t ws_size,
                              hipStream_t stream) {
  const float* x   = (const float*)d_in[0];
  const int*   eli = (const int*)d_in[1];     // int32 per harness contract
  const float* W1  = (const float*)d_in[2];
  const float* b1  = (const float*)d_in[3];
  const float* W2  = (const float*)d_in[4];
  const float* b2  = (const float*)d_in[5];
  float* out = (float*)d_out;

  const int E      = in_sizes[1] / 2;
  const int nNodes = in_sizes[0] / D_FEAT;

  const size_t xbytes = (size_t)nNodes * D_FEAT * 2;   // bf16 copy of x
  const size_t need   = xbytes + 65536;                // + swizzled W1^T
  const bool bfpath   = (ws_size >= need);

  const int grid = (E + EDGES_PER_BLOCK - 1) / EDGES_PER_BLOCK;

  if (bfpath) {
    unsigned short* xbw  = (unsigned short*)d_ws;
    unsigned short* w1tw = (unsigned short*)((char*)d_ws + xbytes);
    int n8 = nNodes * D_FEAT / 8;
    k_cvt_x<<<(n8 + 255) / 256, 256, 0, stream>>>(x, xbw, n8);
    k_cvt_w1<<<16, 256, 0, stream>>>(W1, w1tw);
    k_edge_mlp<true><<<grid, BLOCK_THREADS, 0, stream>>>(
        x, xbw, eli, W1, w1tw, b1, W2, b2, out, E, nNodes);
  } else {
    k_edge_mlp<false><<<grid, BLOCK_THREADS, 0, stream>>>(
        x, nullptr, eli, W1, nullptr, b1, W2, b2, out, E, nNodes);
  }
}